// Round 5
// baseline (250.171 us; speedup 1.0000x reference)
//
#include <hip/hip_runtime.h>

#define HW_IMG (224*224)
#define SCALE 0.17677669529663687f   // 1/sqrt(32)

typedef short bf16x8 __attribute__((ext_vector_type(8)));
typedef float f32x4 __attribute__((ext_vector_type(4)));
union U4B8 { uint4 u; bf16x8 b; };

__device__ __forceinline__ unsigned bf16rn(float f) {
  unsigned u = __float_as_uint(f);
  return (u + 0x7fffu + ((u >> 16) & 1u)) >> 16;
}

// ---- prep1: qh[r] = in_b[r] + query.in_w[r,:]; cb[r] = out_b[r] + out_w[r,:].aob ----
__global__ void prep1_kernel(const float* __restrict__ query,
                             const float* __restrict__ in_w,
                             const float* __restrict__ in_b,
                             const float* __restrict__ out_w,
                             const float* __restrict__ aob,
                             const float* __restrict__ out_b,
                             float* __restrict__ qh,
                             float* __restrict__ cb) {
  const int r = blockIdx.x, tid = threadIdx.x;
  float p1 = query[tid] * in_w[r*256 + tid];
  float p2 = aob[tid]   * out_w[r*256 + tid];
  #pragma unroll
  for (int o = 32; o; o >>= 1) { p1 += __shfl_xor(p1, o); p2 += __shfl_xor(p2, o); }
  __shared__ float t1[4], t2[4];
  if ((tid & 63) == 0) { t1[tid>>6] = p1; t2[tid>>6] = p2; }
  __syncthreads();
  if (tid == 0) qh[r] = in_b[r] + t1[0]+t1[1]+t1[2]+t1[3];
  if (tid == 1) cb[r] = out_b[r] + t2[0]+t2[1]+t2[2]+t2[3];
}

// ---- prep2: qk bf16 B-fragments for mfma_f32_16x16x32_bf16 ----
__global__ void prep2_kernel(const float* __restrict__ qh,
                             const float* __restrict__ in_w,
                             unsigned short* __restrict__ qkf) {
  const int k = blockIdx.x;     // 0..7
  const int L = threadIdx.x;    // 0..63
  const int h = L & 15, q = L >> 4;
  unsigned short o[8];
  #pragma unroll
  for (int j = 0; j < 8; ++j) {
    float s = 0.f;
    if (h < 8) {
      const int c = k*32 + q*8 + j;
      #pragma unroll
      for (int dd = 0; dd < 32; ++dd)
        s += qh[h*32 + dd] * in_w[(256 + h*32 + dd)*256 + c];
      s *= SCALE;
    }
    o[j] = (unsigned short)bf16rn(s);
  }
  ushort4* dst = (ushort4*)(qkf + (size_t)(k*64 + L)*8);
  dst[0] = make_ushort4(o[0],o[1],o[2],o[3]);
  dst[1] = make_ushort4(o[4],o[5],o[6],o[7]);
}

// ---- prep3: wvT and (out_w @ attn_out_w)^T ----
__global__ void prep3_kernel(const float* __restrict__ in_w,
                             const float* __restrict__ aw,
                             const float* __restrict__ out_w,
                             float* __restrict__ wvT,
                             float* __restrict__ cwT) {
  const int o = blockIdx.x, t = threadIdx.x;
  wvT[t*256 + o] = in_w[(512 + o)*256 + t];
  float a = 0.f;
  #pragma unroll 4
  for (int k = 0; k < 256; ++k) a += out_w[o*256 + k] * aw[k*256 + t];
  cwT[t*256 + o] = a;
}

// ---- out transpose: pout[b][pos][c] -> out[b][c][pos] ----
__global__ void transpose_out(const float* __restrict__ pout, float* __restrict__ out) {
  __shared__ float T[64*65];
  const int b  = blockIdx.x;
  const int pc = blockIdx.y;
  const int cc = blockIdx.z;
  const int tid = threadIdx.x;
  const int lc = tid & 63, lr = tid >> 6;
  #pragma unroll
  for (int i = 0; i < 16; ++i) {
    const int p = i*4 + lr;
    T[p*65 + lc] = pout[((size_t)b*256 + pc*64 + p)*256 + cc*64 + lc];
  }
  __syncthreads();
  #pragma unroll
  for (int i = 0; i < 16; ++i) {
    const int c = i*4 + lr;
    out[((size_t)b*256 + cc*64 + c)*256 + pc*64 + lc] = T[lc*65 + c];
  }
}

// ---- main: one block per patch; dbuf bf16 tile; producer waves; 2 barriers/tile ----
__global__ __launch_bounds__(256)
__attribute__((amdgpu_waves_per_eu(2, 8)))
void attnpool_main(
    const float* __restrict__ X,
    const float* __restrict__ in_b,
    const unsigned short* __restrict__ qkf,
    const float* __restrict__ wvT,
    const float* __restrict__ cwT,
    const float* __restrict__ cb,
    float* __restrict__ pout,
    float* __restrict__ out) {
  // bf16 tile: element (r, c) -> u32 word r*160 + (c>>1) + 4*((r>>1)&7), lo = even c
  __shared__ float Xs[2][32*160];     // double-buffered, rows 28..31 zero pad
  __shared__ uint4 QKs[8][64];        // qk B-fragments [kstep][lane]
  __shared__ float Wl[32*8];          // tile alphas (exp vs wave-local max) [l][h]
  __shared__ float Ms[2][8];          // per-wave-half max per head

  const int tid = threadIdx.x;
  const int wid = tid >> 6;
  const int lane = tid & 63;
  const int bid = blockIdx.x;
  const int n = (bid & 7) * 256 + (bid >> 3);   // XCD swizzle (2048%8==0)
  const int b = n >> 8, rem = n & 255, pi = rem >> 4, pj = rem & 15;
  const float* __restrict__ xb = X + (size_t)b*256*HW_IMG + pi*14*224 + pj*14;

  for (int z = tid; z < 640; z += 256) {       // zero pad rows (both buffers)
    Xs[0][28*160 + z] = 0.f;
    Xs[1][28*160 + z] = 0.f;
  }
  {  // stage qk fragments into LDS
    const uint4* qp = (const uint4*)qkf;
    ((uint4*)QKs)[tid]       = qp[tid];
    ((uint4*)QKs)[256 + tid] = qp[256 + tid];
  }

  // ---- producer (waves 2,3) mapping: 14 units/thread; unit -> 2 loads, 2 LDS words ----
  int goff[14], w0s[14];
  unsigned st[28];
  const int lt = tid - 128;
  if (wid >= 2) {
    #pragma unroll
    for (int u = 0; u < 14; ++u) {
      const int e = u*128 + lt;
      const int cp = e / 14, p = e - cp*14;
      const int lr = p / 7, j = p - lr*7;
      goff[u] = (2*cp)*HW_IMG + lr*224 + 2*j;
      w0s[u]  = (2*p)*160 + cp + 4*(p & 7);
    }
  }
  auto stage = [&](int t) {                    // issue loads for tile t, pack bf16
    const float* xt = xb + t*448;
    float2 va[14], vb[14];
    #pragma unroll
    for (int u = 0; u < 14; ++u) {
      va[u] = *(const float2*)(xt + goff[u]);
      vb[u] = *(const float2*)(xt + goff[u] + HW_IMG);
    }
    #pragma unroll
    for (int u = 0; u < 14; ++u) {
      st[2*u]   = bf16rn(va[u].x) | (bf16rn(vb[u].x) << 16);
      st[2*u+1] = bf16rn(va[u].y) | (bf16rn(vb[u].y) << 16);
    }
  };
  auto commit = [&](float* dst) {
    #pragma unroll
    for (int u = 0; u < 14; ++u) {
      ((unsigned*)dst)[w0s[u]]       = st[2*u];
      ((unsigned*)dst)[w0s[u] + 160] = st[2*u+1];
    }
  };

  // score-phase addressing (waves 0,1)
  const int arow = wid*16 + (lane & 15);
  const int abase = arow*640 + (lane>>4)*16 + ((arow>>1)&7)*16;
  const int hcol = lane & 15;
  const int rbase = wid*16 + (lane>>4)*4;

  // pool-phase addressing: all waves; wave -> head pair; lane -> (c-oct, row parity)
  const int o = lane & 31, half = lane >> 5;
  const int pbase = o*16 + half*640;
  const int hA = 2*wid, hB = hA + 1;

  float mA = -INFINITY, mB = -INFINITY, dA = 0.f, dB = 0.f;
  float a0[8] = {0,0,0,0,0,0,0,0}, a1[8] = {0,0,0,0,0,0,0,0};

  // prologue: tile0 -> Xs[0]; issue tile1 loads
  if (wid >= 2) { stage(0); commit(Xs[0]); stage(1); }
  __syncthreads();

  int cur = 0;
  #pragma unroll 1
  for (int t = 0; t < 7; ++t) {
    // ---- segment 1: scores(t) on Xs[cur]  ||  commit(t+1) into Xs[cur^1] ----
    if (wid < 2) {
      f32x4 sc = {0.f, 0.f, 0.f, 0.f};
      const char* xc = (const char*)&Xs[cur][0];
      #pragma unroll
      for (int k = 0; k < 8; ++k) {
        U4B8 a;  a.u  = *(const uint4*)(xc + abase + k*64);
        U4B8 bq; bq.u = QKs[k][lane];
        sc = __builtin_amdgcn_mfma_f32_16x16x32_bf16(a.b, bq.b, sc, 0, 0, 0);
      }
      const bool pad = (wid == 1) && ((lane>>4) == 3);   // rows 28..31
      const float s0 = pad ? -INFINITY : sc[0];
      const float s1 = pad ? -INFINITY : sc[1];
      const float s2 = pad ? -INFINITY : sc[2];
      const float s3 = pad ? -INFINITY : sc[3];
      float mx = fmaxf(fmaxf(s0, s1), fmaxf(s2, s3));
      mx = fmaxf(mx, __shfl_xor(mx, 16));
      mx = fmaxf(mx, __shfl_xor(mx, 32));                // wave-local col max
      const float e0 = __expf(s0 - mx), e1 = __expf(s1 - mx);
      const float e2 = __expf(s2 - mx), e3 = __expf(s3 - mx);
      if (hcol < 8) {
        if (lane < 8) Ms[wid][lane] = mx;
        if (rbase < 28) {
          Wl[(rbase+0)*8 + hcol] = e0;
          Wl[(rbase+1)*8 + hcol] = e1;
          Wl[(rbase+2)*8 + hcol] = e2;
          Wl[(rbase+3)*8 + hcol] = e3;
        }
      }
    } else {
      if (t < 6) commit(&Xs[cur^1][0]);
    }
    __syncthreads();     // scores visible; next tile visible

    // ---- segment 2: pooling(t) on Xs[cur]  ||  producers issue loads(t+2) ----
    {
      const float m0A = Ms[0][hA], m1A = Ms[1][hA];
      const float m0B = Ms[0][hB], m1B = Ms[1][hB];
      const float mnA = fmaxf(fmaxf(m0A, m1A), mA);
      const float mnB = fmaxf(fmaxf(m0B, m1B), mB);
      const float sA = __expf(mA - mnA), sB = __expf(mB - mnB);
      const float fA0 = __expf(m0A - mnA), fA1 = __expf(m1A - mnA);
      const float fB0 = __expf(m0B - mnB), fB1 = __expf(m1B - mnB);
      mA = mnA; mB = mnB;
      dA *= sA; dB *= sB;
      #pragma unroll
      for (int nn = 0; nn < 8; ++nn) { a0[nn] *= sA; a1[nn] *= sB; }
      const char* xc = (const char*)&Xs[cur][0];
      #pragma unroll
      for (int i = 0; i < 14; ++i) {
        const int r = 2*i + half;
        const uint4 xv = *(const uint4*)(xc + pbase + i*1280 + (i&7)*16);
        const float2 w2 = *(const float2*)&Wl[r*8 + hA];
        const float wA = w2.x * (i < 8 ? fA0 : fA1);
        const float wB = w2.y * (i < 8 ? fB0 : fB1);
        dA += wA; dB += wB;
        #pragma unroll
        for (int nn = 0; nn < 4; ++nn) {
          const unsigned uu = ((const unsigned*)&xv)[nn];
          const float xl = __uint_as_float(uu << 16);
          const float xh = __uint_as_float(uu & 0xffff0000u);
          a0[2*nn]   += wA * xl; a0[2*nn+1] += wA * xh;
          a1[2*nn]   += wB * xl; a1[2*nn+1] += wB * xh;
        }
      }
    }
    if (wid >= 2 && t < 5) stage(t+2);
    __syncthreads();     // pooling(t) done; Xs[cur] free for overwrite
    cur ^= 1;
  }

  // ---- epilogue: cross-half reduce, normalize, write pooled to Xs[0] ----
  {
    #pragma unroll
    for (int nn = 0; nn < 8; ++nn) {
      a0[nn] += __shfl_xor(a0[nn], 32);
      a1[nn] += __shfl_xor(a1[nn], 32);
    }
    dA += __shfl_xor(dA, 32);
    dB += __shfl_xor(dB, 32);
    if (half == 0) {
      const float iA = 1.f / dA, iB = 1.f / dB;
      f32x4 t0 = {a0[0]*iA, a0[1]*iA, a0[2]*iA, a0[3]*iA};
      f32x4 t1 = {a0[4]*iA, a0[5]*iA, a0[6]*iA, a0[7]*iA};
      f32x4 t2 = {a1[0]*iB, a1[1]*iB, a1[2]*iB, a1[3]*iB};
      f32x4 t3 = {a1[4]*iB, a1[5]*iB, a1[6]*iB, a1[7]*iB};
      *(f32x4*)&Xs[0][hA*256 + 8*o]     = t0;
      *(f32x4*)&Xs[0][hA*256 + 8*o + 4] = t1;
      *(f32x4*)&Xs[0][hB*256 + 8*o]     = t2;
      *(f32x4*)&Xs[0][hB*256 + 8*o + 4] = t3;
    }
  }
  __syncthreads();
  {  // ctx[c'] = bv[c'] + sum_c wvT[c][c'] * pooled[h(c')][c]
    const int h2 = tid >> 5;
    float a = in_b[512 + tid];
    #pragma unroll 8
    for (int c = 0; c < 256; ++c) a += wvT[c*256 + tid] * Xs[0][h2*256 + c];
    Xs[0][2048 + tid] = a;
  }
  __syncthreads();
  {  // out[o'] = cb[o'] + sum_k cwT[k][o'] * ctx[k]
    float oo = cb[tid];
    #pragma unroll 8
    for (int k = 0; k < 256; ++k) oo += cwT[k*256 + tid] * Xs[0][2048 + k];
    if (pout) pout[(size_t)n*256 + tid] = oo;                   // coalesced
    else out[(((size_t)b*256 + tid)*16 + pi)*16 + pj] = oo;     // fallback
  }
}

extern "C" void kernel_launch(void* const* d_in, const int* in_sizes, int n_in,
                              void* d_out, int out_size, void* d_ws, size_t ws_size,
                              hipStream_t stream) {
  const float* X    = (const float*)d_in[0];
  const float* q    = (const float*)d_in[1];
  const float* in_w = (const float*)d_in[2];
  const float* in_b = (const float*)d_in[3];
  const float* aw   = (const float*)d_in[4];
  const float* aob  = (const float*)d_in[5];
  const float* ow   = (const float*)d_in[6];
  const float* ob   = (const float*)d_in[7];
  float* out = (float*)d_out;

  float* wsf = (float*)d_ws;
  float* qh   = wsf;                        // 256
  float* cb   = wsf + 256;                  // 256
  unsigned short* qkf = (unsigned short*)(wsf + 512);  // 8KB
  float* wvT  = wsf + 4096;                 // 65536
  float* cwT  = wsf + 4096 + 65536;         // 65536
  const size_t need = (size_t)(4096 + 2*65536 + 2048*256) * sizeof(float);
  float* pout = (ws_size >= need) ? (wsf + 4096 + 2*65536) : nullptr;  // 2 MB

  hipLaunchKernelGGL(prep1_kernel, dim3(256),  dim3(256), 0, stream,
                     q, in_w, in_b, ow, aob, ob, qh, cb);
  hipLaunchKernelGGL(prep2_kernel, dim3(8),    dim3(64),  0, stream,
                     qh, in_w, qkf);
  hipLaunchKernelGGL(prep3_kernel, dim3(256),  dim3(256), 0, stream,
                     in_w, aw, ow, wvT, cwT);
  hipLaunchKernelGGL(attnpool_main, dim3(2048), dim3(256), 0, stream,
                     X, in_b, qkf, wvT, cwT, cb, pout, out);
  if (pout)
    hipLaunchKernelGGL(transpose_out, dim3(8, 4, 4), dim3(256), 0, stream,
                       pout, out);
}